// Round 1
// baseline (4551.976 us; speedup 1.0000x reference)
//
#include <hip/hip_runtime.h>
#include <hip/hip_bf16.h>

#define NA 35
#define NM 18
#define NN 53
#define TT 48
#define HH 32
#define OUT_MEO_BASE (1024*35*32)
#define XHS 72     // xh row stride in u16 (144 B: 16B-aligned, not a 128B multiple -> 2-way LDS conflicts only)

typedef unsigned short u16;
typedef __attribute__((ext_vector_type(8))) short s8v;   // 8 bf16 (4 VGPRs) MFMA A/B frag
typedef __attribute__((ext_vector_type(4))) float f4v;   // MFMA C/D frag

__device__ __forceinline__ float bfu(u16 u){ return __uint_as_float(((unsigned)u)<<16); }
__device__ __forceinline__ float flo(unsigned u){ return __uint_as_float(u<<16); }
__device__ __forceinline__ float fhi(unsigned u){ return __uint_as_float(u & 0xFFFF0000u); }
__device__ __forceinline__ u16 cvtbf(float f){
  unsigned u = __float_as_uint(f);
  return (u16)((u + 0x7FFFu + ((u>>16)&1u)) >> 16);   // round-to-nearest-even
}

struct Params {
  const void *X_aqi, *X_meo, *ctx, *adj, *adjn;
  const void *emb0,*emb1,*emb2,*emb3,*emb4,*emb5,*emb6,*emb7,*emb8;
  const void *Wxa,*Wxm,*Wua,*Wum;
  const void *a0,*a1,*a2,*a3;
  const void *wih_a,*whh_a,*bih_a,*bhh_a,*wih_m,*whh_m,*bih_m,*bhh_m;
  const int *Xae,*Xme;
  void* out;
};

__device__ __forceinline__ float ldf(const void* p, int i, bool isbf){
  return isbf ? bfu(((const u16*)p)[i]) : ((const float*)p)[i];
}
__device__ __forceinline__ u16 ldraw(const void* p, int i, bool isbf){
  return isbf ? ((const u16*)p)[i] : cvtbf(((const float*)p)[i]);
}

// ~50 KB static LDS. GRU weight B-fragments are RE-LOADED from global each
// timestep (contiguous 16B per lane, L1/L2-hot, only 24 KB shared by all
// blocks) instead of living in 64 resident VGPRs: resident-register diet is
// what buys 2 blocks/CU residency (grid drains in 2 rounds, not 4).
struct __align__(16) Smem {
  alignas(16) float gb[4][96];       // bih_a, bhh_a, bih_m, bhh_m (fp32)
  alignas(16) float Wxa[6*32], Wxm[4*32];
  alignas(16) float aAll[4][188];
  alignas(16) float embA[304];
  alignas(16) float ctxS[NN][2], ctxD[NN][2];
  alignas(16) float uSrc[2][2][14];
  alignas(16) float uDst[2][2][14];
  alignas(16) u16   biasE[NN*56];    // bf16: adj_norm*a[184] or -1e12
  alignas(16) float xin[NN*16];
  alignas(16) u16   attri_bf[32*60]; // transposed [d][n], bf16, stride 60
  alignas(16) float srcv[NN*2], dstv[NN*2];
  alignas(16) float p[NN*56];        // softmax numerators fp32 (cols 53-55 zeroed)
  alignas(16) float inv[56];
  alignas(16) u16   xh[64*XHS];      // MFMA A operand: [row n][0:32)=gx bf16, [32:64)=h bf16; rows 53-63 + cols 64-71 zero
  alignas(16) float h[NN*32];        // fp32 hidden state (carry precision)
};

// (256,2): min 2 waves/EU -> unified VGPR+AGPR capped at 256/wave -> 2 blocks/CU.
// The old (,2) spills were caused by the 64 resident bfr VGPRs, now removed;
// peak pressure is confined to ph5 (12 transient frags + accumulators).
__global__ __launch_bounds__(256, 2)
void chgat_gru_kernel(Params p){
  __shared__ Smem sm;
  const int tid = threadIdx.x;
  const int b = blockIdx.x;

  // ---------- stage 0: dtype detection (adj is exactly {0,1}) ----------
  bool isbf = false;
  {
    const unsigned* aw = (const unsigned*)p.adj;
    for (int i=0;i<32;++i){
      unsigned w = aw[i];
      if (w != 0u && w != 0x3F800000u) isbf = true;
    }
  }

  // ---------- stage 1: stage constants into LDS ----------
  if (tid < 96){
    sm.gb[0][tid]=ldf(p.bih_a,tid,isbf); sm.gb[1][tid]=ldf(p.bhh_a,tid,isbf);
    sm.gb[2][tid]=ldf(p.bih_m,tid,isbf); sm.gb[3][tid]=ldf(p.bhh_m,tid,isbf);
  }
  if (tid < 192) sm.Wxa[tid] = ldf(p.Wxa, tid, isbf);
  if (tid < 128) sm.Wxm[tid] = ldf(p.Wxm, tid, isbf);
  if (tid < 185){
    sm.aAll[0][tid] = ldf(p.a0, tid, isbf);
    sm.aAll[1][tid] = ldf(p.a1, tid, isbf);
    sm.aAll[2][tid] = ldf(p.a2, tid, isbf);
    sm.aAll[3][tid] = ldf(p.a3, tid, isbf);
  }
  if (tid < 70)  sm.embA[tid]        = ldf(p.emb0, tid, isbf);
  if (tid < 26)  sm.embA[70+tid]     = ldf(p.emb1, tid, isbf);
  if (tid < 14)  sm.embA[96+tid]     = ldf(p.emb2, tid, isbf);
  if (tid < 48)  sm.embA[110+tid]    = ldf(p.emb3, tid, isbf);
  if (tid < 18)  sm.embA[158+tid]    = ldf(p.emb4, tid, isbf);
  if (tid < 36)  sm.embA[176+tid]    = ldf(p.emb5, tid, isbf);
  if (tid < 26)  sm.embA[212+tid]    = ldf(p.emb6, tid, isbf);
  if (tid < 14)  sm.embA[238+tid]    = ldf(p.emb7, tid, isbf);
  if (tid < 48)  sm.embA[252+tid]    = ldf(p.emb8, tid, isbf);
  for (int idx=tid; idx<NN*32; idx+=256) sm.h[idx] = 0.f;
  for (int idx=tid; idx<64*XHS; idx+=256) sm.xh[idx] = 0;   // h=0 at t=0; pad rows/cols stay 0
  if (tid < 159){ int rr=tid/3, cc=53+tid%3; sm.p[rr*56+cc] = 0.f; }
  if (tid < 224){ int rr=tid/7, cc=53+tid%7; sm.attri_bf[rr*60+cc] = 0; }
  __syncthreads();

  // ---------- stage 2: batch-invariant attention constants ----------
  if (tid < 212){
    int i = tid>>2, v = tid&3, it = (i<NA)?0:1;
    float s = 0.f;
    if (v < 2){
      const float* ac = &sm.aAll[it*2+v][32];
      for (int c=0;c<60;++c) s += ldf(p.ctx, i*60+c, isbf)*ac[c];
      sm.ctxS[i][v] = s;
    } else {
      const float* ac = &sm.aAll[(v-2)*2+it][124];
      for (int c=0;c<60;++c) s += ldf(p.ctx, i*60+c, isbf)*ac[c];
      sm.ctxD[i][v-2] = s;
    }
  }
  if (tid < 112){
    int u = tid;
    int it = u / 56, rem = u % 56;
    int sd = rem / 28, rem2 = rem % 28;
    int v = rem2 / 14, k = rem2 % 14;
    const void* Wu = it ? p.Wum : p.Wua;
    const float* av = sd ? &sm.aAll[v*2+it][92] : &sm.aAll[it*2+v][0];
    float s = 0.f;
    for (int kk=0;kk<32;++kk) s += ldf(Wu, k*32+kk, isbf)*av[kk];
    if (sd) sm.uDst[it][v][k] = s; else sm.uSrc[it][v][k] = s;
  }
  for (int idx=tid; idx<NN*NN; idx+=256){
    int i = idx/NN, j = idx - i*NN;
    int sel = ((i<NA)?0:2) + ((j<NA)?0:1);
    float ad = ldf(p.adj, idx, isbf);
    sm.biasE[i*56+j] = cvtbf((ad > 0.f) ? ldf(p.adjn, idx, isbf)*sm.aAll[sel][184] : -1e12f);
  }
  __syncthreads();

  const int ng   = tid >> 6;        // wave 0..3
  const int hs   = (tid >> 5) & 1;  // half-wave (ph4)
  const int d    = tid & 31;        // dim (ph4)
  const int lane = tid & 63;
  const int nl   = lane & 15;       // MFMA col/row-in-tile index
  const int qd   = lane >> 4;       // MFMA quad

  // Per-wave weight type: waves 0-2 aqi, wave 3 meo (its both M-passes are meo).
  const int wty = (ng==3) ? 1 : 0;
  const void* wih_g = wty ? p.wih_m : p.wih_a;
  const void* whh_g = wty ? p.whh_m : p.whh_a;

  // ---------- prefetch t=0 (512 slots over 256 threads) ----------
  float rv1 = 0.f, rv2r = 0.f; int rv2i = 0;
  {
    int bt = b*TT + 0;
    rv1 = (tid < 210) ? ldf(p.X_aqi, bt*210 + tid, isbf) : ldf(p.X_meo, bt*72 + tid - 210, isbf);
    if (tid < 26) rv2r = ldf(p.X_meo, bt*72 + tid + 46, isbf);
    else { int u = tid - 26; rv2i = (u < 140) ? p.Xae[bt*140 + u] : p.Xme[bt*90 + u - 140]; }
  }

  #pragma unroll 1
  for (int t=0; t<TT; ++t){
    // ---- ph0: scatter prefetched inputs into xin ----
    if (tid < 210) sm.xin[(tid/6)*16 + tid%6] = rv1;
    else { int q = tid-210; sm.xin[(NA + (q>>2))*16 + (q&3)] = rv1; }
    if (tid < 26){ int q = tid + 46; sm.xin[(NA + (q>>2))*16 + (q&3)] = rv2r; }
    else {
      int u = tid - 26;
      if (u < 140){
        int n = u>>2, e = u&3;
        int off = (e==0)?0:(e==1)?70:(e==2)?96:110;
        sm.xin[n*16 + 6 + 2*e]     = sm.embA[off + rv2i*2];
        sm.xin[n*16 + 6 + 2*e + 1] = sm.embA[off + rv2i*2 + 1];
      } else {
        int q = u - 140;
        int n = NA + q/5, e = q%5;
        int off = (e==0)?158:(e==1)?176:(e==2)?212:(e==3)?238:252;
        sm.xin[n*16 + 4 + 2*e]     = sm.embA[off + rv2i*2];
        sm.xin[n*16 + 4 + 2*e + 1] = sm.embA[off + rv2i*2 + 1];
      }
    }
    // prefetch t+1
    {
      int tn = (t < TT-1) ? t+1 : t;
      int bt = b*TT + tn;
      rv1 = (tid < 210) ? ldf(p.X_aqi, bt*210 + tid, isbf) : ldf(p.X_meo, bt*72 + tid - 210, isbf);
      if (tid < 26) rv2r = ldf(p.X_meo, bt*72 + tid + 46, isbf);
      else { int u = tid - 26; rv2i = (u < 140) ? p.Xae[bt*140 + u] : p.Xme[bt*90 + u - 140]; }
    }
    __syncthreads();   // (A) xin ready; prior-step h writes visible to all waves

    // ---- ph1: attri_t (bf16, transposed) + src/dst logits ----
    for (int it = tid; it < 1908; it += 256){
      if (it < 1696){
        int n = it>>5, dj = it&31;
        const float* x = &sm.xin[n*16];
        float at = 0.f;
        if (n < NA){
          #pragma unroll
          for (int k=0;k<6;++k) at += x[k]*sm.Wxa[k*32+dj];
        } else {
          #pragma unroll
          for (int k=0;k<4;++k) at += x[k]*sm.Wxm[k*32+dj];
        }
        sm.attri_bf[dj*60 + n] = cvtbf(at);
      } else {
        int u = it - 1696;
        int i = u>>2, v = u&3, it2 = (i<NA)?0:1;
        const float* x = &sm.xin[i*16];
        float sacc; const float* uv;
        if (v < 2){ sacc = sm.ctxS[i][v];   uv = sm.uSrc[it2][v]; }
        else      { sacc = sm.ctxD[i][v-2]; uv = sm.uDst[it2][v-2]; }
        #pragma unroll
        for (int k=0;k<14;++k) sacc += x[k]*uv[k];
        if (v < 2) sm.srcv[i*2+v] = sacc; else sm.dstv[i*2+(v-2)] = sacc;
      }
    }
    __syncthreads();   // (B) attri_t, srcv, dstv ready

    // ---- ph3: masked softmax rows (4 lanes/row; e staged in LDS) ----
    if (tid < 212){
      int i = tid>>2, l = tid&3, it2 = (i<NA)?0:1;
      float s0 = sm.srcv[i*2+0], s1 = sm.srcv[i*2+1];
      float mx = -3.0e38f;
      for (int j=l; j<NN; j+=4){
        float e = ((j<NA)? s0 : s1) + sm.dstv[j*2+it2] + bfu(sm.biasE[i*56+j]);
        e = (e >= 0.f) ? e : 0.2f*e;
        sm.p[i*56+j] = e;
        mx = fmaxf(mx, e);
      }
      mx = fmaxf(mx, __shfl_xor(mx,1,64));
      mx = fmaxf(mx, __shfl_xor(mx,2,64));
      float sum = 0.f;
      for (int j=l; j<NN; j+=4){
        float pe = __expf(sm.p[i*56+j] - mx);
        sm.p[i*56+j] = pe;
        sum += pe;
      }
      sum += __shfl_xor(sum,1,64);
      sum += __shfl_xor(sum,2,64);
      if (l == 0) sm.inv[i] = 1.0f/sum;
    }
    __syncthreads();   // (C) p, inv ready

    // ---- ph4: gx = softmax @ attri -> bf16 into xh[:, 0:32) ----
    {
      const int nb = ng + 4*hs;   // rows nb, nb+8, ..., nb+48
      float c0=0.f,c1=0.f,c2=0.f,c3=0.f,c4=0.f,c5=0.f,c6=0.f;
      #pragma unroll
      for (int jc=0; jc<14; ++jc){
        uint2 ab = *(const uint2*)&sm.attri_bf[d*60 + jc*4];
        float a0=flo(ab.x), a1=fhi(ab.x), a2=flo(ab.y), a3=fhi(ab.y);
        const float* pc = &sm.p[jc*4];
        { float4 q=*(const float4*)&pc[(nb   )*56]; c0 += q.x*a0+q.y*a1+q.z*a2+q.w*a3; }
        { float4 q=*(const float4*)&pc[(nb+ 8)*56]; c1 += q.x*a0+q.y*a1+q.z*a2+q.w*a3; }
        { float4 q=*(const float4*)&pc[(nb+16)*56]; c2 += q.x*a0+q.y*a1+q.z*a2+q.w*a3; }
        { float4 q=*(const float4*)&pc[(nb+24)*56]; c3 += q.x*a0+q.y*a1+q.z*a2+q.w*a3; }
        { float4 q=*(const float4*)&pc[(nb+32)*56]; c4 += q.x*a0+q.y*a1+q.z*a2+q.w*a3; }
        { float4 q=*(const float4*)&pc[(nb+40)*56]; c5 += q.x*a0+q.y*a1+q.z*a2+q.w*a3; }
        if (nb+48 <= 52){ float4 q=*(const float4*)&pc[(nb+48)*56]; c6 += q.x*a0+q.y*a1+q.z*a2+q.w*a3; }
      }
      sm.xh[(nb   )*XHS + d] = cvtbf(c0*sm.inv[nb]);
      sm.xh[(nb+ 8)*XHS + d] = cvtbf(c1*sm.inv[nb+8]);
      sm.xh[(nb+16)*XHS + d] = cvtbf(c2*sm.inv[nb+16]);
      sm.xh[(nb+24)*XHS + d] = cvtbf(c3*sm.inv[nb+24]);
      sm.xh[(nb+32)*XHS + d] = cvtbf(c4*sm.inv[nb+32]);
      sm.xh[(nb+40)*XHS + d] = cvtbf(c5*sm.inv[nb+40]);
      if (nb+48 <= 52) sm.xh[(nb+48)*XHS + d] = cvtbf(c6*sm.inv[nb+48]);
    }

    // ---- ph4.5: issue the 12 GRU weight B-fragments from GLOBAL (L1/L2-hot;
    // 16B contiguous per lane since wih/whh are [96][32] row-major). Issued
    // before barrier D so the load latency drains with the barrier. These are
    // transient registers (dead after ph5) -> resident pressure stays low.
    // Frag f (gate-row tile r0 = f*16): lane value W[(r0+nl)][qd*8 .. qd*8+7].
    // fw[0..3]/fh[0..3]: r,z gates (k<32 from wih, k>=32 from whh);
    // fw[4..5]: i-gate x-part (wih rows 64..95, k<32 only — k>=32 half was 0);
    // fh[4..5]: n-gate h-part (whh rows 64..95, k>=32 only — k<32 half was 0).
    s8v fw[6], fh[6];
    {
      const int fo = nl*32 + qd*8;
      if (isbf){
        const u16* wi = (const u16*)wih_g; const u16* wh = (const u16*)whh_g;
        #pragma unroll
        for (int f=0; f<6; ++f){
          fw[f] = *(const s8v*)(wi + f*512 + fo);
          fh[f] = *(const s8v*)(wh + f*512 + fo);
        }
      } else {
        const float* wi = (const float*)wih_g; const float* wh = (const float*)whh_g;
        #pragma unroll
        for (int f=0; f<6; ++f){
          float4 a0 = *(const float4*)(wi + f*512 + fo);
          float4 a1 = *(const float4*)(wi + f*512 + fo + 4);
          float4 b0 = *(const float4*)(wh + f*512 + fo);
          float4 b1 = *(const float4*)(wh + f*512 + fo + 4);
          s8v v, w;
          v[0]=(short)cvtbf(a0.x); v[1]=(short)cvtbf(a0.y); v[2]=(short)cvtbf(a0.z); v[3]=(short)cvtbf(a0.w);
          v[4]=(short)cvtbf(a1.x); v[5]=(short)cvtbf(a1.y); v[6]=(short)cvtbf(a1.z); v[7]=(short)cvtbf(a1.w);
          w[0]=(short)cvtbf(b0.x); w[1]=(short)cvtbf(b0.y); w[2]=(short)cvtbf(b0.z); w[3]=(short)cvtbf(b0.w);
          w[4]=(short)cvtbf(b1.x); w[5]=(short)cvtbf(b1.y); w[6]=(short)cvtbf(b1.z); w[7]=(short)cvtbf(b1.w);
          fw[f] = v; fh[f] = w;
        }
      }
    }
    __syncthreads();   // (D) xh x-part ready for all waves' A-fragments

    // ---- ph5: GRU via MFMA. D[53x128] = xh[53x64] @ B[64x128], epilogue elementwise ----
    // 12 MFMAs/pass (the 4 structurally-zero half-tiles of the old 16 are dropped).
    {
      const bool last = (t == TT-1);
      auto run_pass = [&](int mt, int tp){
        const u16* xr = &sm.xh[(mt*16 + nl)*XHS + qd*8];
        s8v A0 = *(const s8v*)xr;          // k 0..31 (x)
        s8v A1 = *(const s8v*)(xr + 32);   // k 32..63 (h)
        f4v aR0={0,0,0,0}, aR1={0,0,0,0}, aZ0={0,0,0,0}, aZ1={0,0,0,0};
        f4v aI0={0,0,0,0}, aI1={0,0,0,0}, aG0={0,0,0,0}, aG1={0,0,0,0};
        aR0 = __builtin_amdgcn_mfma_f32_16x16x32_bf16(A0, fw[0], aR0, 0,0,0);
        aR0 = __builtin_amdgcn_mfma_f32_16x16x32_bf16(A1, fh[0], aR0, 0,0,0);
        aR1 = __builtin_amdgcn_mfma_f32_16x16x32_bf16(A0, fw[1], aR1, 0,0,0);
        aR1 = __builtin_amdgcn_mfma_f32_16x16x32_bf16(A1, fh[1], aR1, 0,0,0);
        aZ0 = __builtin_amdgcn_mfma_f32_16x16x32_bf16(A0, fw[2], aZ0, 0,0,0);
        aZ0 = __builtin_amdgcn_mfma_f32_16x16x32_bf16(A1, fh[2], aZ0, 0,0,0);
        aZ1 = __builtin_amdgcn_mfma_f32_16x16x32_bf16(A0, fw[3], aZ1, 0,0,0);
        aZ1 = __builtin_amdgcn_mfma_f32_16x16x32_bf16(A1, fh[3], aZ1, 0,0,0);
        aI0 = __builtin_amdgcn_mfma_f32_16x16x32_bf16(A0, fw[4], aI0, 0,0,0);
        aI1 = __builtin_amdgcn_mfma_f32_16x16x32_bf16(A0, fw[5], aI1, 0,0,0);
        aG0 = __builtin_amdgcn_mfma_f32_16x16x32_bf16(A1, fh[4], aG0, 0,0,0);
        aG1 = __builtin_amdgcn_mfma_f32_16x16x32_bf16(A1, fh[5], aG1, 0,0,0);
        const float* bi = tp ? sm.gb[2] : sm.gb[0];
        const float* bh = tp ? sm.gb[3] : sm.gb[1];
        const int d0 = nl, d1 = nl + 16;
        float br0=bi[d0]+bh[d0], bz0=bi[32+d0]+bh[32+d0], bn0=bi[64+d0], bg0=bh[64+d0];
        float br1=bi[d1]+bh[d1], bz1=bi[32+d1]+bh[32+d1], bn1=bi[64+d1], bg1=bh[64+d1];
        #pragma unroll
        for (int r=0;r<4;++r){
          int node = mt*16 + qd*4 + r;      // C/D layout: row=(lane>>4)*4+reg
          bool valid = tp ? (node>=NA && node<NN) : (node<NA);
          if (valid){
            float hold0 = sm.h[node*32+d0];
            float hold1 = sm.h[node*32+d1];
            float rr0 = 1.f/(1.f+__expf(-(aR0[r]+br0)));
            float zz0 = 1.f/(1.f+__expf(-(aZ0[r]+bz0)));
            float pr0 = (aI0[r]+bn0) + rr0*(aG0[r]+bg0);
            float e20 = __expf(2.f*pr0);
            float hn0 = (1.f-zz0)*(1.f-2.f/(e20+1.f)) + zz0*hold0;
            float rr1 = 1.f/(1.f+__expf(-(aR1[r]+br1)));
            float zz1 = 1.f/(1.f+__expf(-(aZ1[r]+bz1)));
            float pr1 = (aI1[r]+bn1) + rr1*(aG1[r]+bg1);
            float e21 = __expf(2.f*pr1);
            float hn1 = (1.f-zz1)*(1.f-2.f/(e21+1.f)) + zz1*hold1;
            sm.h[node*32+d0] = hn0;
            sm.h[node*32+d1] = hn1;
            sm.xh[node*XHS+32+d0] = cvtbf(hn0);
            sm.xh[node*XHS+32+d1] = cvtbf(hn1);
            if (last){
              long long oi = tp ? ((long long)OUT_MEO_BASE + (long long)b*(NM*HH) + (long long)(node-NA)*32)
                                : ((long long)b*(NA*HH) + (long long)node*32);
              if (isbf){ ((u16*)p.out)[oi+d0]=cvtbf(hn0); ((u16*)p.out)[oi+d1]=cvtbf(hn1); }
              else     { ((float*)p.out)[oi+d0]=hn0; ((float*)p.out)[oi+d1]=hn1; }
            }
          }
        }
      };
      if      (ng==0) run_pass(0,0);
      else if (ng==1) run_pass(1,0);
      else if (ng==2) run_pass(2,0);          // mixed tile, aqi rows 32-34
      else { run_pass(2,1); run_pass(3,1); }  // mixed tile meo rows 35-47; tile3 rows 48-52
    }
    // loop tail: epilogue h writes ordered vs next step's readers by barrier (A)
  }
}

extern "C" void kernel_launch(void* const* d_in, const int* in_sizes, int n_in,
                              void* d_out, int out_size, void* d_ws, size_t ws_size,
                              hipStream_t stream){
  (void)in_sizes; (void)n_in; (void)d_ws; (void)ws_size; (void)out_size;
  Params p;
  p.X_aqi = d_in[0];
  p.X_meo = d_in[1];
  p.ctx   = d_in[2];
  p.adj   = d_in[3];
  p.adjn  = d_in[4];
  p.emb0 = d_in[5];  p.emb1 = d_in[6];
  p.emb2 = d_in[7];  p.emb3 = d_in[8];
  p.emb4 = d_in[9];  p.emb5 = d_in[10];
  p.emb6 = d_in[11]; p.emb7 = d_in[12];
  p.emb8 = d_in[13];
  p.Wxa = d_in[14]; p.Wxm = d_in[15];
  p.Wua = d_in[16]; p.Wum = d_in[17];
  p.a0 = d_in[18]; p.a1 = d_in[19];
  p.a2 = d_in[20]; p.a3 = d_in[21];
  p.wih_a = d_in[22]; p.whh_a = d_in[23];
  p.bih_a = d_in[24]; p.bhh_a = d_in[25];
  p.wih_m = d_in[26]; p.whh_m = d_in[27];
  p.bih_m = d_in[28]; p.bhh_m = d_in[29];
  p.Xae = (const int*)d_in[30];
  p.Xme = (const int*)d_in[31];
  p.out = d_out;
  hipLaunchKernelGGL(chgat_gru_kernel, dim3(1024), dim3(256), 0, stream, p);
}

// Round 2
// 4288.582 us; speedup vs baseline: 1.0614x; 1.0614x over previous
//
#include <hip/hip_runtime.h>
#include <hip/hip_bf16.h>

#define NA 35
#define NM 18
#define NN 53
#define TT 48
#define HH 32
#define OUT_MEO_BASE (1024*35*32)
#define XHS 72     // xh row stride in u16 (144 B: 16B-aligned, not a 128B multiple -> 2-way LDS conflicts only)

typedef unsigned short u16;
typedef __attribute__((ext_vector_type(8))) short s8v;   // 8 bf16 (4 VGPRs) MFMA A/B frag
typedef __attribute__((ext_vector_type(4))) float f4v;   // MFMA C/D frag

__device__ __forceinline__ float bfu(u16 u){ return __uint_as_float(((unsigned)u)<<16); }
__device__ __forceinline__ float flo(unsigned u){ return __uint_as_float(u<<16); }
__device__ __forceinline__ float fhi(unsigned u){ return __uint_as_float(u & 0xFFFF0000u); }
__device__ __forceinline__ u16 cvtbf(float f){
  unsigned u = __float_as_uint(f);
  return (u16)((u + 0x7FFFu + ((u>>16)&1u)) >> 16);   // round-to-nearest-even
}

struct Params {
  const void *X_aqi, *X_meo, *ctx, *adj, *adjn;
  const void *emb0,*emb1,*emb2,*emb3,*emb4,*emb5,*emb6,*emb7,*emb8;
  const void *Wxa,*Wxm,*Wua,*Wum;
  const void *a0,*a1,*a2,*a3;
  const void *wih_a,*whh_a,*bih_a,*bhh_a,*wih_m,*whh_m,*bih_m,*bhh_m;
  const int *Xae,*Xme;
  void* out;
};

__device__ __forceinline__ float ldf(const void* p, int i, bool isbf){
  return isbf ? bfu(((const u16*)p)[i]) : ((const float*)p)[i];
}
__device__ __forceinline__ u16 ldraw(const void* p, int i, bool isbf){
  return isbf ? ((const u16*)p)[i] : cvtbf(((const float*)p)[i]);
}

// ~75 KB static LDS (x2 blocks = 150.6 KB <= 160 KB/CU). GRU weight
// B-fragments live in LDS in FRAGMENT ORDER (wfrag): per-lane read address is
// lane*16B + const -> each 16-lane group covers all 32 banks -> conflict-free
// ds_read_b128. Zero resident weight VGPRs: that is what lets the kernel fit
// the 128-VGPR tier (2 blocks/CU) WITHOUT the round-1 scratch-spill disaster.
struct __align__(16) Smem {
  alignas(16) float gb[4][96];       // bih_a, bhh_a, bih_m, bhh_m (fp32)
  alignas(16) float Wxa[6*32], Wxm[4*32];
  alignas(16) float aAll[4][188];
  alignas(16) float embA[304];
  alignas(16) float ctxS[NN][2], ctxD[NN][2];
  alignas(16) float uSrc[2][2][14];
  alignas(16) float uDst[2][2][14];
  alignas(16) u16   biasE[NN*56];    // bf16: adj_norm*a[184] or -1e12
  alignas(16) float xin[NN*16];
  alignas(16) u16   attri_bf[32*60]; // transposed [d][n], bf16, stride 60
  alignas(16) float srcv[NN*2], dstv[NN*2];
  alignas(16) float p[NN*56];        // softmax numerators fp32 (cols 53-55 zeroed)
  alignas(16) float inv[56];
  alignas(16) u16   xh[64*XHS];      // MFMA A operand: [row n][0:32)=gx bf16, [32:64)=h bf16; rows 53-63 + cols 64-71 zero
  alignas(16) float h[NN*32];        // fp32 hidden state (carry precision)
  alignas(16) u16   wfrag[2*12*64*8]; // B-frags, fragment-ordered: ((wty*12+f)*64+lane)*8
                                      // f 0..5 = fw (wih rows f*16+nl, cols qd*8..+7)
                                      // f 6..11 = fh (whh rows (f-6)*16+nl)
};

// (256,2): compiler caps arch VGPRs at 128 -> 2 blocks/CU (measured r1:
// VGPR_Count=128, Occupancy 24%). Round-1 spilled because 48 weight VGPRs
// were live across barrier D; now ph5 pressure is transient-only.
__global__ __launch_bounds__(256, 2)
void chgat_gru_kernel(Params p){
  __shared__ Smem sm;
  const int tid = threadIdx.x;
  const int b = blockIdx.x;

  // ---------- stage 0: dtype detection (adj is exactly {0,1}) ----------
  bool isbf = false;
  {
    const unsigned* aw = (const unsigned*)p.adj;
    for (int i=0;i<32;++i){
      unsigned w = aw[i];
      if (w != 0u && w != 0x3F800000u) isbf = true;
    }
  }

  // ---------- stage 1: stage constants into LDS ----------
  if (tid < 96){
    sm.gb[0][tid]=ldf(p.bih_a,tid,isbf); sm.gb[1][tid]=ldf(p.bhh_a,tid,isbf);
    sm.gb[2][tid]=ldf(p.bih_m,tid,isbf); sm.gb[3][tid]=ldf(p.bhh_m,tid,isbf);
  }
  if (tid < 192) sm.Wxa[tid] = ldf(p.Wxa, tid, isbf);
  if (tid < 128) sm.Wxm[tid] = ldf(p.Wxm, tid, isbf);
  if (tid < 185){
    sm.aAll[0][tid] = ldf(p.a0, tid, isbf);
    sm.aAll[1][tid] = ldf(p.a1, tid, isbf);
    sm.aAll[2][tid] = ldf(p.a2, tid, isbf);
    sm.aAll[3][tid] = ldf(p.a3, tid, isbf);
  }
  if (tid < 70)  sm.embA[tid]        = ldf(p.emb0, tid, isbf);
  if (tid < 26)  sm.embA[70+tid]     = ldf(p.emb1, tid, isbf);
  if (tid < 14)  sm.embA[96+tid]     = ldf(p.emb2, tid, isbf);
  if (tid < 48)  sm.embA[110+tid]    = ldf(p.emb3, tid, isbf);
  if (tid < 18)  sm.embA[158+tid]    = ldf(p.emb4, tid, isbf);
  if (tid < 36)  sm.embA[176+tid]    = ldf(p.emb5, tid, isbf);
  if (tid < 26)  sm.embA[212+tid]    = ldf(p.emb6, tid, isbf);
  if (tid < 14)  sm.embA[238+tid]    = ldf(p.emb7, tid, isbf);
  if (tid < 48)  sm.embA[252+tid]    = ldf(p.emb8, tid, isbf);
  for (int idx=tid; idx<NN*32; idx+=256) sm.h[idx] = 0.f;
  for (int idx=tid; idx<64*XHS; idx+=256) sm.xh[idx] = 0;   // h=0 at t=0; pad rows/cols stay 0
  if (tid < 159){ int rr=tid/3, cc=53+tid%3; sm.p[rr*56+cc] = 0.f; }
  if (tid < 224){ int rr=tid/7, cc=53+tid%7; sm.attri_bf[rr*60+cc] = 0; }
  // GRU weights -> LDS, fragment-ordered (once; 6 lane-frags per thread)
  for (int u = tid; u < 2*12*64; u += 256){
    int wty2 = u / (12*64);
    int rem  = u - wty2*(12*64);
    int f = rem >> 6, l = rem & 63;
    int nl2 = l & 15, qd2 = l >> 4;
    const void* W = (f < 6) ? (wty2 ? p.wih_m : p.wih_a) : (wty2 ? p.whh_m : p.whh_a);
    int fr = (f < 6) ? f : f - 6;
    int base = (fr*16 + nl2)*32 + qd2*8;
    u16* dst = &sm.wfrag[u*8];
    #pragma unroll
    for (int j=0;j<8;++j) dst[j] = ldraw(W, base+j, isbf);
  }
  __syncthreads();

  // ---------- stage 2: batch-invariant attention constants ----------
  if (tid < 212){
    int i = tid>>2, v = tid&3, it = (i<NA)?0:1;
    float s = 0.f;
    if (v < 2){
      const float* ac = &sm.aAll[it*2+v][32];
      for (int c=0;c<60;++c) s += ldf(p.ctx, i*60+c, isbf)*ac[c];
      sm.ctxS[i][v] = s;
    } else {
      const float* ac = &sm.aAll[(v-2)*2+it][124];
      for (int c=0;c<60;++c) s += ldf(p.ctx, i*60+c, isbf)*ac[c];
      sm.ctxD[i][v-2] = s;
    }
  }
  if (tid < 112){
    int u = tid;
    int it = u / 56, rem = u % 56;
    int sd = rem / 28, rem2 = rem % 28;
    int v = rem2 / 14, k = rem2 % 14;
    const void* Wu = it ? p.Wum : p.Wua;
    const float* av = sd ? &sm.aAll[v*2+it][92] : &sm.aAll[it*2+v][0];
    float s = 0.f;
    for (int kk=0;kk<32;++kk) s += ldf(Wu, k*32+kk, isbf)*av[kk];
    if (sd) sm.uDst[it][v][k] = s; else sm.uSrc[it][v][k] = s;
  }
  for (int idx=tid; idx<NN*NN; idx+=256){
    int i = idx/NN, j = idx - i*NN;
    int sel = ((i<NA)?0:2) + ((j<NA)?0:1);
    float ad = ldf(p.adj, idx, isbf);
    sm.biasE[i*56+j] = cvtbf((ad > 0.f) ? ldf(p.adjn, idx, isbf)*sm.aAll[sel][184] : -1e12f);
  }
  __syncthreads();

  const int ng   = tid >> 6;        // wave 0..3
  const int hs   = (tid >> 5) & 1;  // half-wave (ph4)
  const int d    = tid & 31;        // dim (ph4)
  const int lane = tid & 63;
  const int nl   = lane & 15;       // MFMA col/row-in-tile index
  const int qd   = lane >> 4;       // MFMA quad

  // Per-wave weight type: waves 0-2 aqi, wave 3 meo (its both M-passes are meo).
  const int wty = (ng==3) ? 1 : 0;
  // Per-lane B-frag base (s8v units): frag f lives at wfB[f*64]
  const s8v* wfB = ((const s8v*)sm.wfrag) + (wty*12*64 + lane);

  // ---------- prefetch t=0 (512 slots over 256 threads) ----------
  float rv1 = 0.f, rv2r = 0.f; int rv2i = 0;
  {
    int bt = b*TT + 0;
    rv1 = (tid < 210) ? ldf(p.X_aqi, bt*210 + tid, isbf) : ldf(p.X_meo, bt*72 + tid - 210, isbf);
    if (tid < 26) rv2r = ldf(p.X_meo, bt*72 + tid + 46, isbf);
    else { int u = tid - 26; rv2i = (u < 140) ? p.Xae[bt*140 + u] : p.Xme[bt*90 + u - 140]; }
  }

  #pragma unroll 1
  for (int t=0; t<TT; ++t){
    // ---- ph0: scatter prefetched inputs into xin ----
    if (tid < 210) sm.xin[(tid/6)*16 + tid%6] = rv1;
    else { int q = tid-210; sm.xin[(NA + (q>>2))*16 + (q&3)] = rv1; }
    if (tid < 26){ int q = tid + 46; sm.xin[(NA + (q>>2))*16 + (q&3)] = rv2r; }
    else {
      int u = tid - 26;
      if (u < 140){
        int n = u>>2, e = u&3;
        int off = (e==0)?0:(e==1)?70:(e==2)?96:110;
        sm.xin[n*16 + 6 + 2*e]     = sm.embA[off + rv2i*2];
        sm.xin[n*16 + 6 + 2*e + 1] = sm.embA[off + rv2i*2 + 1];
      } else {
        int q = u - 140;
        int n = NA + q/5, e = q%5;
        int off = (e==0)?158:(e==1)?176:(e==2)?212:(e==3)?238:252;
        sm.xin[n*16 + 4 + 2*e]     = sm.embA[off + rv2i*2];
        sm.xin[n*16 + 4 + 2*e + 1] = sm.embA[off + rv2i*2 + 1];
      }
    }
    // prefetch t+1
    {
      int tn = (t < TT-1) ? t+1 : t;
      int bt = b*TT + tn;
      rv1 = (tid < 210) ? ldf(p.X_aqi, bt*210 + tid, isbf) : ldf(p.X_meo, bt*72 + tid - 210, isbf);
      if (tid < 26) rv2r = ldf(p.X_meo, bt*72 + tid + 46, isbf);
      else { int u = tid - 26; rv2i = (u < 140) ? p.Xae[bt*140 + u] : p.Xme[bt*90 + u - 140]; }
    }
    __syncthreads();   // (A) xin ready; prior-step h writes visible to all waves

    // ---- ph1: attri_t (bf16, transposed) + src/dst logits ----
    for (int it = tid; it < 1908; it += 256){
      if (it < 1696){
        int n = it>>5, dj = it&31;
        const float* x = &sm.xin[n*16];
        float at = 0.f;
        if (n < NA){
          #pragma unroll
          for (int k=0;k<6;++k) at += x[k]*sm.Wxa[k*32+dj];
        } else {
          #pragma unroll
          for (int k=0;k<4;++k) at += x[k]*sm.Wxm[k*32+dj];
        }
        sm.attri_bf[dj*60 + n] = cvtbf(at);
      } else {
        int u = it - 1696;
        int i = u>>2, v = u&3, it2 = (i<NA)?0:1;
        const float* x = &sm.xin[i*16];
        float sacc; const float* uv;
        if (v < 2){ sacc = sm.ctxS[i][v];   uv = sm.uSrc[it2][v]; }
        else      { sacc = sm.ctxD[i][v-2]; uv = sm.uDst[it2][v-2]; }
        #pragma unroll
        for (int k=0;k<14;++k) sacc += x[k]*uv[k];
        if (v < 2) sm.srcv[i*2+v] = sacc; else sm.dstv[i*2+(v-2)] = sacc;
      }
    }
    __syncthreads();   // (B) attri_t, srcv, dstv ready

    // ---- ph3: masked softmax rows (4 lanes/row; e staged in LDS) ----
    if (tid < 212){
      int i = tid>>2, l = tid&3, it2 = (i<NA)?0:1;
      float s0 = sm.srcv[i*2+0], s1 = sm.srcv[i*2+1];
      float mx = -3.0e38f;
      for (int j=l; j<NN; j+=4){
        float e = ((j<NA)? s0 : s1) + sm.dstv[j*2+it2] + bfu(sm.biasE[i*56+j]);
        e = (e >= 0.f) ? e : 0.2f*e;
        sm.p[i*56+j] = e;
        mx = fmaxf(mx, e);
      }
      mx = fmaxf(mx, __shfl_xor(mx,1,64));
      mx = fmaxf(mx, __shfl_xor(mx,2,64));
      float sum = 0.f;
      for (int j=l; j<NN; j+=4){
        float pe = __expf(sm.p[i*56+j] - mx);
        sm.p[i*56+j] = pe;
        sum += pe;
      }
      sum += __shfl_xor(sum,1,64);
      sum += __shfl_xor(sum,2,64);
      if (l == 0) sm.inv[i] = 1.0f/sum;
    }
    __syncthreads();   // (C) p, inv ready

    // ---- ph4: gx = softmax @ attri -> bf16 into xh[:, 0:32) ----
    {
      const int nb = ng + 4*hs;   // rows nb, nb+8, ..., nb+48
      float c0=0.f,c1=0.f,c2=0.f,c3=0.f,c4=0.f,c5=0.f,c6=0.f;
      #pragma unroll
      for (int jc=0; jc<14; ++jc){
        uint2 ab = *(const uint2*)&sm.attri_bf[d*60 + jc*4];
        float a0=flo(ab.x), a1=fhi(ab.x), a2=flo(ab.y), a3=fhi(ab.y);
        const float* pc = &sm.p[jc*4];
        { float4 q=*(const float4*)&pc[(nb   )*56]; c0 += q.x*a0+q.y*a1+q.z*a2+q.w*a3; }
        { float4 q=*(const float4*)&pc[(nb+ 8)*56]; c1 += q.x*a0+q.y*a1+q.z*a2+q.w*a3; }
        { float4 q=*(const float4*)&pc[(nb+16)*56]; c2 += q.x*a0+q.y*a1+q.z*a2+q.w*a3; }
        { float4 q=*(const float4*)&pc[(nb+24)*56]; c3 += q.x*a0+q.y*a1+q.z*a2+q.w*a3; }
        { float4 q=*(const float4*)&pc[(nb+32)*56]; c4 += q.x*a0+q.y*a1+q.z*a2+q.w*a3; }
        { float4 q=*(const float4*)&pc[(nb+40)*56]; c5 += q.x*a0+q.y*a1+q.z*a2+q.w*a3; }
        if (nb+48 <= 52){ float4 q=*(const float4*)&pc[(nb+48)*56]; c6 += q.x*a0+q.y*a1+q.z*a2+q.w*a3; }
      }
      sm.xh[(nb   )*XHS + d] = cvtbf(c0*sm.inv[nb]);
      sm.xh[(nb+ 8)*XHS + d] = cvtbf(c1*sm.inv[nb+8]);
      sm.xh[(nb+16)*XHS + d] = cvtbf(c2*sm.inv[nb+16]);
      sm.xh[(nb+24)*XHS + d] = cvtbf(c3*sm.inv[nb+24]);
      sm.xh[(nb+32)*XHS + d] = cvtbf(c4*sm.inv[nb+32]);
      sm.xh[(nb+40)*XHS + d] = cvtbf(c5*sm.inv[nb+40]);
      if (nb+48 <= 52) sm.xh[(nb+48)*XHS + d] = cvtbf(c6*sm.inv[nb+48]);
    }
    __syncthreads();   // (D) xh x-part ready for all waves' A-fragments

    // ---- ph5: GRU via MFMA, B-frags streamed from LDS (conflict-free).
    // Two sequential half-passes (output dims nl / nl+16) keep concurrent
    // pressure to {A0,A1, 4 accums, <=6 frags} -> fits the 128-VGPR cap.
    {
      const bool last = (t == TT-1);
      auto run_pass = [&](int mt, int tp){
        const u16* xr = &sm.xh[(mt*16 + nl)*XHS + qd*8];
        s8v A0 = *(const s8v*)xr;          // k 0..31 (x)
        s8v A1 = *(const s8v*)(xr + 32);   // k 32..63 (h)
        const float* bi = tp ? sm.gb[2] : sm.gb[0];
        const float* bh = tp ? sm.gb[3] : sm.gb[1];
        #pragma unroll 1
        for (int hf=0; hf<2; ++hf){
          f4v aR={0,0,0,0}, aZ={0,0,0,0}, aI={0,0,0,0}, aG={0,0,0,0};
          aR = __builtin_amdgcn_mfma_f32_16x16x32_bf16(A0, wfB[(0+hf)*64],  aR, 0,0,0);
          aR = __builtin_amdgcn_mfma_f32_16x16x32_bf16(A1, wfB[(6+hf)*64],  aR, 0,0,0);
          aZ = __builtin_amdgcn_mfma_f32_16x16x32_bf16(A0, wfB[(2+hf)*64],  aZ, 0,0,0);
          aZ = __builtin_amdgcn_mfma_f32_16x16x32_bf16(A1, wfB[(8+hf)*64],  aZ, 0,0,0);
          aI = __builtin_amdgcn_mfma_f32_16x16x32_bf16(A0, wfB[(4+hf)*64],  aI, 0,0,0);
          aG = __builtin_amdgcn_mfma_f32_16x16x32_bf16(A1, wfB[(10+hf)*64], aG, 0,0,0);
          const int dd = nl + hf*16;
          float br=bi[dd]+bh[dd], bz=bi[32+dd]+bh[32+dd], bn=bi[64+dd], bg=bh[64+dd];
          #pragma unroll
          for (int r=0;r<4;++r){
            int node = mt*16 + qd*4 + r;      // C/D layout: row=(lane>>4)*4+reg
            bool valid = tp ? (node>=NA && node<NN) : (node<NA);
            if (valid){
              float hold = sm.h[node*32+dd];
              float rr = 1.f/(1.f+__expf(-(aR[r]+br)));
              float zz = 1.f/(1.f+__expf(-(aZ[r]+bz)));
              float pr = (aI[r]+bn) + rr*(aG[r]+bg);
              float e2 = __expf(2.f*pr);
              float hn = (1.f-zz)*(1.f-2.f/(e2+1.f)) + zz*hold;
              sm.h[node*32+dd] = hn;
              sm.xh[node*XHS+32+dd] = cvtbf(hn);
              if (last){
                long long oi = tp ? ((long long)OUT_MEO_BASE + (long long)b*(NM*HH) + (long long)(node-NA)*32)
                                  : ((long long)b*(NA*HH) + (long long)node*32);
                if (isbf) ((u16*)p.out)[oi+dd]=cvtbf(hn);
                else      ((float*)p.out)[oi+dd]=hn;
              }
            }
          }
        }
      };
      if      (ng==0) run_pass(0,0);
      else if (ng==1) run_pass(1,0);
      else if (ng==2) run_pass(2,0);          // mixed tile, aqi rows 32-34
      else { run_pass(2,1); run_pass(3,1); }  // mixed tile meo rows 35-47; tile3 rows 48-52
    }
    // loop tail: epilogue h writes ordered vs next step's readers by barrier (A)
  }
}

extern "C" void kernel_launch(void* const* d_in, const int* in_sizes, int n_in,
                              void* d_out, int out_size, void* d_ws, size_t ws_size,
                              hipStream_t stream){
  (void)in_sizes; (void)n_in; (void)d_ws; (void)ws_size; (void)out_size;
  Params p;
  p.X_aqi = d_in[0];
  p.X_meo = d_in[1];
  p.ctx   = d_in[2];
  p.adj   = d_in[3];
  p.adjn  = d_in[4];
  p.emb0 = d_in[5];  p.emb1 = d_in[6];
  p.emb2 = d_in[7];  p.emb3 = d_in[8];
  p.emb4 = d_in[9];  p.emb5 = d_in[10];
  p.emb6 = d_in[11]; p.emb7 = d_in[12];
  p.emb8 = d_in[13];
  p.Wxa = d_in[14]; p.Wxm = d_in[15];
  p.Wua = d_in[16]; p.Wum = d_in[17];
  p.a0 = d_in[18]; p.a1 = d_in[19];
  p.a2 = d_in[20]; p.a3 = d_in[21];
  p.wih_a = d_in[22]; p.whh_a = d_in[23];
  p.bih_a = d_in[24]; p.bhh_a = d_in[25];
  p.wih_m = d_in[26]; p.whh_m = d_in[27];
  p.bih_m = d_in[28]; p.bhh_m = d_in[29];
  p.Xae = (const int*)d_in[30];
  p.Xme = (const int*)d_in[31];
  p.out = d_out;
  hipLaunchKernelGGL(chgat_gru_kernel, dim3(1024), dim3(256), 0, stream, p);
}

// Round 3
// 1715.430 us; speedup vs baseline: 2.6535x; 2.5000x over previous
//
#include <hip/hip_runtime.h>
#include <hip/hip_bf16.h>

#define NA 35
#define NM 18
#define NN 53
#define TT 48
#define HH 32
#define OUT_MEO_BASE (1024*35*32)
#define XHS 72     // xh row stride in u16 (144 B: 16B-aligned, not a 128B multiple -> 2-way LDS conflicts only)

typedef unsigned short u16;
typedef __attribute__((ext_vector_type(8))) short s8v;   // 8 bf16 (4 VGPRs) MFMA A/B frag
typedef __attribute__((ext_vector_type(4))) float f4v;   // MFMA C/D frag

__device__ __forceinline__ float bfu(u16 u){ return __uint_as_float(((unsigned)u)<<16); }
__device__ __forceinline__ float flo(unsigned u){ return __uint_as_float(u<<16); }
__device__ __forceinline__ float fhi(unsigned u){ return __uint_as_float(u & 0xFFFF0000u); }
__device__ __forceinline__ u16 cvtbf(float f){
  unsigned u = __float_as_uint(f);
  return (u16)((u + 0x7FFFu + ((u>>16)&1u)) >> 16);   // round-to-nearest-even
}

struct Params {
  const void *X_aqi, *X_meo, *ctx, *adj, *adjn;
  const void *emb0,*emb1,*emb2,*emb3,*emb4,*emb5,*emb6,*emb7,*emb8;
  const void *Wxa,*Wxm,*Wua,*Wum;
  const void *a0,*a1,*a2,*a3;
  const void *wih_a,*whh_a,*bih_a,*bhh_a,*wih_m,*whh_m,*bih_m,*bhh_m;
  const int *Xae,*Xme;
  void* out;
};

__device__ __forceinline__ float ldf(const void* p, int i, bool isbf){
  return isbf ? bfu(((const u16*)p)[i]) : ((const float*)p)[i];
}
__device__ __forceinline__ u16 ldraw(const void* p, int i, bool isbf){
  return isbf ? ((const u16*)p)[i] : cvtbf(((const float*)p)[i]);
}

// ~75 KB static LDS. GRU weight B-fragments live in LDS in FRAGMENT ORDER
// (wfrag): per-lane read address is lane*16B + const -> each 16-lane group
// covers all 32 banks -> conflict-free ds_read_b128.
struct __align__(16) Smem {
  alignas(16) float gb[4][96];       // bih_a, bhh_a, bih_m, bhh_m (fp32)
  alignas(16) float Wxa[6*32], Wxm[4*32];
  alignas(16) float aAll[4][188];
  alignas(16) float embA[304];
  alignas(16) float ctxS[NN][2], ctxD[NN][2];
  alignas(16) float uSrc[2][2][14];
  alignas(16) float uDst[2][2][14];
  alignas(16) u16   biasE[NN*56];    // bf16: adj_norm*a[184] or -1e12
  alignas(16) float xin[NN*16];
  alignas(16) u16   attri_bf[32*60]; // transposed [d][n], bf16, stride 60
  alignas(16) float srcv[NN*2], dstv[NN*2];
  alignas(16) float p[NN*56];        // softmax numerators fp32 (cols 53-55 zeroed)
  alignas(16) float inv[56];
  alignas(16) u16   xh[64*XHS];      // MFMA A operand: [row n][0:32)=gx bf16, [32:64)=h bf16; rows 53-63 + cols 64-71 zero
  alignas(16) float h[NN*32];        // fp32 hidden state (carry precision)
  alignas(16) u16   wfrag[2*12*64*8]; // B-frags, fragment-ordered: ((wty*12+f)*64+lane)*8
                                      // f 0..5 = fw (wih rows f*16+nl, cols qd*8..+7)
                                      // f 6..11 = fh (whh rows (f-6)*16+nl)
};

// 512-thread blocks (8 waves), one batch element per block. The block NEEDS
// 2 waves/SIMD to be resident at all, so the compiler is forced to fit
// arch+AGPR <= 256/wave -- double the r1/r2 128-cap that caused 12 GB of
// scratch spill, while per-thread work halves. 8 waves/CU = 24% occupancy
// from a single block, spill-free. No second launch_bounds arg: the block
// shape itself enforces the cap.
__global__ __launch_bounds__(512)
void chgat_gru_kernel(Params p){
  __shared__ Smem sm;
  const int tid = threadIdx.x;
  const int b = blockIdx.x;

  // ---------- stage 0: dtype detection (adj is exactly {0,1}) ----------
  bool isbf = false;
  {
    const unsigned* aw = (const unsigned*)p.adj;
    for (int i=0;i<32;++i){
      unsigned w = aw[i];
      if (w != 0u && w != 0x3F800000u) isbf = true;
    }
  }

  // ---------- stage 1: stage constants into LDS ----------
  if (tid < 96){
    sm.gb[0][tid]=ldf(p.bih_a,tid,isbf); sm.gb[1][tid]=ldf(p.bhh_a,tid,isbf);
    sm.gb[2][tid]=ldf(p.bih_m,tid,isbf); sm.gb[3][tid]=ldf(p.bhh_m,tid,isbf);
  }
  if (tid < 192) sm.Wxa[tid] = ldf(p.Wxa, tid, isbf);
  if (tid < 128) sm.Wxm[tid] = ldf(p.Wxm, tid, isbf);
  if (tid < 185){
    sm.aAll[0][tid] = ldf(p.a0, tid, isbf);
    sm.aAll[1][tid] = ldf(p.a1, tid, isbf);
    sm.aAll[2][tid] = ldf(p.a2, tid, isbf);
    sm.aAll[3][tid] = ldf(p.a3, tid, isbf);
  }
  if (tid < 70)  sm.embA[tid]        = ldf(p.emb0, tid, isbf);
  if (tid < 26)  sm.embA[70+tid]     = ldf(p.emb1, tid, isbf);
  if (tid < 14)  sm.embA[96+tid]     = ldf(p.emb2, tid, isbf);
  if (tid < 48)  sm.embA[110+tid]    = ldf(p.emb3, tid, isbf);
  if (tid < 18)  sm.embA[158+tid]    = ldf(p.emb4, tid, isbf);
  if (tid < 36)  sm.embA[176+tid]    = ldf(p.emb5, tid, isbf);
  if (tid < 26)  sm.embA[212+tid]    = ldf(p.emb6, tid, isbf);
  if (tid < 14)  sm.embA[238+tid]    = ldf(p.emb7, tid, isbf);
  if (tid < 48)  sm.embA[252+tid]    = ldf(p.emb8, tid, isbf);
  for (int idx=tid; idx<NN*32; idx+=512) sm.h[idx] = 0.f;
  for (int idx=tid; idx<64*XHS; idx+=512) sm.xh[idx] = 0;   // h=0 at t=0; pad rows/cols stay 0
  if (tid < 159){ int rr=tid/3, cc=53+tid%3; sm.p[rr*56+cc] = 0.f; }
  if (tid < 224){ int rr=tid/7, cc=53+tid%7; sm.attri_bf[rr*60+cc] = 0; }
  // GRU weights -> LDS, fragment-ordered (once; 3 lane-frags per thread)
  for (int u = tid; u < 2*12*64; u += 512){
    int wty2 = u / (12*64);
    int rem  = u - wty2*(12*64);
    int f = rem >> 6, l = rem & 63;
    int nl2 = l & 15, qd2 = l >> 4;
    const void* W = (f < 6) ? (wty2 ? p.wih_m : p.wih_a) : (wty2 ? p.whh_m : p.whh_a);
    int fr = (f < 6) ? f : f - 6;
    int base = (fr*16 + nl2)*32 + qd2*8;
    u16* dst = &sm.wfrag[u*8];
    #pragma unroll
    for (int j=0;j<8;++j) dst[j] = ldraw(W, base+j, isbf);
  }
  __syncthreads();

  // ---------- stage 2: batch-invariant attention constants ----------
  if (tid < 212){
    int i = tid>>2, v = tid&3, it = (i<NA)?0:1;
    float s = 0.f;
    if (v < 2){
      const float* ac = &sm.aAll[it*2+v][32];
      for (int c=0;c<60;++c) s += ldf(p.ctx, i*60+c, isbf)*ac[c];
      sm.ctxS[i][v] = s;
    } else {
      const float* ac = &sm.aAll[(v-2)*2+it][124];
      for (int c=0;c<60;++c) s += ldf(p.ctx, i*60+c, isbf)*ac[c];
      sm.ctxD[i][v-2] = s;
    }
  }
  if (tid < 112){
    int u = tid;
    int it = u / 56, rem = u % 56;
    int sd = rem / 28, rem2 = rem % 28;
    int v = rem2 / 14, k = rem2 % 14;
    const void* Wu = it ? p.Wum : p.Wua;
    const float* av = sd ? &sm.aAll[v*2+it][92] : &sm.aAll[it*2+v][0];
    float s = 0.f;
    for (int kk=0;kk<32;++kk) s += ldf(Wu, k*32+kk, isbf)*av[kk];
    if (sd) sm.uDst[it][v][k] = s; else sm.uSrc[it][v][k] = s;
  }
  for (int idx=tid; idx<NN*NN; idx+=512){
    int i = idx/NN, j = idx - i*NN;
    int sel = ((i<NA)?0:2) + ((j<NA)?0:1);
    float ad = ldf(p.adj, idx, isbf);
    sm.biasE[i*56+j] = cvtbf((ad > 0.f) ? ldf(p.adjn, idx, isbf)*sm.aAll[sel][184] : -1e12f);
  }
  __syncthreads();

  const int ng   = tid >> 6;        // wave 0..7
  const int lane = tid & 63;
  const int nl   = lane & 15;       // MFMA col/row-in-tile index
  const int qd   = lane >> 4;       // MFMA quad
  const int d    = tid & 31;        // dim (ph4)

  // ph5 wave->pass map: 5 passes over 5 waves (max ONE pass per wave).
  // waves 0-2: aqi tiles 0,1,2; wave 3: tile2 meo rows; wave 4: tile3 meo.
  const int wty = (ng==3 || ng==4) ? 1 : 0;
  // Per-lane B-frag base (s8v units): frag f lives at wfB[f*64]
  const s8v* wfB = ((const s8v*)sm.wfrag) + (wty*12*64 + lane);

  // ---------- prefetch t=0 (512 slots over 512 threads, one each) ----------
  float rvf = 0.f; int rvi = 0;
  {
    int bt = b*TT + 0;
    if      (tid < 210) rvf = ldf(p.X_aqi, bt*210 + tid, isbf);
    else if (tid < 282) rvf = ldf(p.X_meo, bt*72 + tid - 210, isbf);
    else if (tid < 422) rvi = p.Xae[bt*140 + tid - 282];
    else                rvi = p.Xme[bt*90  + tid - 422];
  }

  #pragma unroll 1
  for (int t=0; t<TT; ++t){
    // ---- ph0: scatter prefetched inputs into xin ----
    if (tid < 210) sm.xin[(tid/6)*16 + tid%6] = rvf;
    else if (tid < 282){ int q = tid-210; sm.xin[(NA + (q>>2))*16 + (q&3)] = rvf; }
    else if (tid < 422){
      int u = tid - 282;
      int n = u>>2, e = u&3;
      int off = (e==0)?0:(e==1)?70:(e==2)?96:110;
      sm.xin[n*16 + 6 + 2*e]     = sm.embA[off + rvi*2];
      sm.xin[n*16 + 6 + 2*e + 1] = sm.embA[off + rvi*2 + 1];
    } else {
      int q = tid - 422;
      int n = NA + q/5, e = q%5;
      int off = (e==0)?158:(e==1)?176:(e==2)?212:(e==3)?238:252;
      sm.xin[n*16 + 4 + 2*e]     = sm.embA[off + rvi*2];
      sm.xin[n*16 + 4 + 2*e + 1] = sm.embA[off + rvi*2 + 1];
    }
    // prefetch t+1
    {
      int tn = (t < TT-1) ? t+1 : t;
      int bt = b*TT + tn;
      if      (tid < 210) rvf = ldf(p.X_aqi, bt*210 + tid, isbf);
      else if (tid < 282) rvf = ldf(p.X_meo, bt*72 + tid - 210, isbf);
      else if (tid < 422) rvi = p.Xae[bt*140 + tid - 282];
      else                rvi = p.Xme[bt*90  + tid - 422];
    }
    __syncthreads();   // (A) xin ready; prior-step h writes visible to all waves

    // ---- ph1: attri_t (bf16, transposed) + src/dst logits ----
    for (int it = tid; it < 1908; it += 512){
      if (it < 1696){
        int n = it>>5, dj = it&31;
        const float* x = &sm.xin[n*16];
        float at = 0.f;
        if (n < NA){
          #pragma unroll
          for (int k=0;k<6;++k) at += x[k]*sm.Wxa[k*32+dj];
        } else {
          #pragma unroll
          for (int k=0;k<4;++k) at += x[k]*sm.Wxm[k*32+dj];
        }
        sm.attri_bf[dj*60 + n] = cvtbf(at);
      } else {
        int u = it - 1696;
        int i = u>>2, v = u&3, it2 = (i<NA)?0:1;
        const float* x = &sm.xin[i*16];
        float sacc; const float* uv;
        if (v < 2){ sacc = sm.ctxS[i][v];   uv = sm.uSrc[it2][v]; }
        else      { sacc = sm.ctxD[i][v-2]; uv = sm.uDst[it2][v-2]; }
        #pragma unroll
        for (int k=0;k<14;++k) sacc += x[k]*uv[k];
        if (v < 2) sm.srcv[i*2+v] = sacc; else sm.dstv[i*2+(v-2)] = sacc;
      }
    }
    __syncthreads();   // (B) attri_t, srcv, dstv ready

    // ---- ph3: masked softmax rows (8 lanes/row; e staged in LDS) ----
    if (tid < 424){
      int i = tid>>3, l = tid&7, it2 = (i<NA)?0:1;
      float s0 = sm.srcv[i*2+0], s1 = sm.srcv[i*2+1];
      float mx = -3.0e38f;
      for (int j=l; j<NN; j+=8){
        float e = ((j<NA)? s0 : s1) + sm.dstv[j*2+it2] + bfu(sm.biasE[i*56+j]);
        e = (e >= 0.f) ? e : 0.2f*e;
        sm.p[i*56+j] = e;
        mx = fmaxf(mx, e);
      }
      mx = fmaxf(mx, __shfl_xor(mx,1,64));
      mx = fmaxf(mx, __shfl_xor(mx,2,64));
      mx = fmaxf(mx, __shfl_xor(mx,4,64));
      float sum = 0.f;
      for (int j=l; j<NN; j+=8){
        float pe = __expf(sm.p[i*56+j] - mx);
        sm.p[i*56+j] = pe;
        sum += pe;
      }
      sum += __shfl_xor(sum,1,64);
      sum += __shfl_xor(sum,2,64);
      sum += __shfl_xor(sum,4,64);
      if (l == 0) sm.inv[i] = 1.0f/sum;
    }
    __syncthreads();   // (C) p, inv ready

    // ---- ph4: gx = softmax @ attri -> bf16 into xh[:, 0:32) ----
    // 512 threads: nb = tid>>5 in 0..15; rows nb, nb+16, nb+32, nb+48(<=52).
    {
      const int nb = tid >> 5;
      float c0=0.f,c1=0.f,c2=0.f,c3=0.f;
      #pragma unroll
      for (int jc=0; jc<14; ++jc){
        uint2 ab = *(const uint2*)&sm.attri_bf[d*60 + jc*4];
        float a0=flo(ab.x), a1=fhi(ab.x), a2=flo(ab.y), a3=fhi(ab.y);
        const float* pc = &sm.p[jc*4];
        { float4 q=*(const float4*)&pc[(nb   )*56]; c0 += q.x*a0+q.y*a1+q.z*a2+q.w*a3; }
        { float4 q=*(const float4*)&pc[(nb+16)*56]; c1 += q.x*a0+q.y*a1+q.z*a2+q.w*a3; }
        { float4 q=*(const float4*)&pc[(nb+32)*56]; c2 += q.x*a0+q.y*a1+q.z*a2+q.w*a3; }
        if (nb+48 <= 52){ float4 q=*(const float4*)&pc[(nb+48)*56]; c3 += q.x*a0+q.y*a1+q.z*a2+q.w*a3; }
      }
      sm.xh[(nb   )*XHS + d] = cvtbf(c0*sm.inv[nb]);
      sm.xh[(nb+16)*XHS + d] = cvtbf(c1*sm.inv[nb+16]);
      sm.xh[(nb+32)*XHS + d] = cvtbf(c2*sm.inv[nb+32]);
      if (nb+48 <= 52) sm.xh[(nb+48)*XHS + d] = cvtbf(c3*sm.inv[nb+48]);
    }
    __syncthreads();   // (D) xh x-part ready for all waves' A-fragments

    // ---- ph5: GRU via MFMA, B-frags streamed from LDS (conflict-free).
    // One pass per wave (waves 0-4); both output halves unrolled for ILP.
    {
      const bool last = (t == TT-1);
      auto run_pass = [&](int mt, int tp){
        const u16* xr = &sm.xh[(mt*16 + nl)*XHS + qd*8];
        s8v A0 = *(const s8v*)xr;          // k 0..31 (x)
        s8v A1 = *(const s8v*)(xr + 32);   // k 32..63 (h)
        f4v aR0={0,0,0,0}, aR1={0,0,0,0}, aZ0={0,0,0,0}, aZ1={0,0,0,0};
        f4v aI0={0,0,0,0}, aI1={0,0,0,0}, aG0={0,0,0,0}, aG1={0,0,0,0};
        aR0 = __builtin_amdgcn_mfma_f32_16x16x32_bf16(A0, wfB[0*64],  aR0, 0,0,0);
        aR0 = __builtin_amdgcn_mfma_f32_16x16x32_bf16(A1, wfB[6*64],  aR0, 0,0,0);
        aR1 = __builtin_amdgcn_mfma_f32_16x16x32_bf16(A0, wfB[1*64],  aR1, 0,0,0);
        aR1 = __builtin_amdgcn_mfma_f32_16x16x32_bf16(A1, wfB[7*64],  aR1, 0,0,0);
        aZ0 = __builtin_amdgcn_mfma_f32_16x16x32_bf16(A0, wfB[2*64],  aZ0, 0,0,0);
        aZ0 = __builtin_amdgcn_mfma_f32_16x16x32_bf16(A1, wfB[8*64],  aZ0, 0,0,0);
        aZ1 = __builtin_amdgcn_mfma_f32_16x16x32_bf16(A0, wfB[3*64],  aZ1, 0,0,0);
        aZ1 = __builtin_amdgcn_mfma_f32_16x16x32_bf16(A1, wfB[9*64],  aZ1, 0,0,0);
        aI0 = __builtin_amdgcn_mfma_f32_16x16x32_bf16(A0, wfB[4*64],  aI0, 0,0,0);
        aI1 = __builtin_amdgcn_mfma_f32_16x16x32_bf16(A0, wfB[5*64],  aI1, 0,0,0);
        aG0 = __builtin_amdgcn_mfma_f32_16x16x32_bf16(A1, wfB[10*64], aG0, 0,0,0);
        aG1 = __builtin_amdgcn_mfma_f32_16x16x32_bf16(A1, wfB[11*64], aG1, 0,0,0);
        const float* bi = tp ? sm.gb[2] : sm.gb[0];
        const float* bh = tp ? sm.gb[3] : sm.gb[1];
        const int d0 = nl, d1 = nl + 16;
        float br0=bi[d0]+bh[d0], bz0=bi[32+d0]+bh[32+d0], bn0=bi[64+d0], bg0=bh[64+d0];
        float br1=bi[d1]+bh[d1], bz1=bi[32+d1]+bh[32+d1], bn1=bi[64+d1], bg1=bh[64+d1];
        #pragma unroll
        for (int r=0;r<4;++r){
          int node = mt*16 + qd*4 + r;      // C/D layout: row=(lane>>4)*4+reg
          bool valid = tp ? (node>=NA && node<NN) : (node<NA);
          if (valid){
            float hold0 = sm.h[node*32+d0];
            float hold1 = sm.h[node*32+d1];
            float rr0 = 1.f/(1.f+__expf(-(aR0[r]+br0)));
            float zz0 = 1.f/(1.f+__expf(-(aZ0[r]+bz0)));
            float pr0 = (aI0[r]+bn0) + rr0*(aG0[r]+bg0);
            float e20 = __expf(2.f*pr0);
            float hn0 = (1.f-zz0)*(1.f-2.f/(e20+1.f)) + zz0*hold0;
            float rr1 = 1.f/(1.f+__expf(-(aR1[r]+br1)));
            float zz1 = 1.f/(1.f+__expf(-(aZ1[r]+bz1)));
            float pr1 = (aI1[r]+bn1) + rr1*(aG1[r]+bg1);
            float e21 = __expf(2.f*pr1);
            float hn1 = (1.f-zz1)*(1.f-2.f/(e21+1.f)) + zz1*hold1;
            sm.h[node*32+d0] = hn0;
            sm.h[node*32+d1] = hn1;
            sm.xh[node*XHS+32+d0] = cvtbf(hn0);
            sm.xh[node*XHS+32+d1] = cvtbf(hn1);
            if (last){
              long long oi = tp ? ((long long)OUT_MEO_BASE + (long long)b*(NM*HH) + (long long)(node-NA)*32)
                                : ((long long)b*(NA*HH) + (long long)node*32);
              if (isbf){ ((u16*)p.out)[oi+d0]=cvtbf(hn0); ((u16*)p.out)[oi+d1]=cvtbf(hn1); }
              else     { ((float*)p.out)[oi+d0]=hn0; ((float*)p.out)[oi+d1]=hn1; }
            }
          }
        }
      };
      if      (ng==0) run_pass(0,0);
      else if (ng==1) run_pass(1,0);
      else if (ng==2) run_pass(2,0);   // mixed tile, aqi rows 32-34
      else if (ng==3) run_pass(2,1);   // mixed tile, meo rows 35-47
      else if (ng==4) run_pass(3,1);   // tile3, meo rows 48-52
      // waves 5-7 idle in ph5
    }
    // loop tail: epilogue h writes ordered vs next step's readers by barrier (A)
  }
}

extern "C" void kernel_launch(void* const* d_in, const int* in_sizes, int n_in,
                              void* d_out, int out_size, void* d_ws, size_t ws_size,
                              hipStream_t stream){
  (void)in_sizes; (void)n_in; (void)d_ws; (void)ws_size; (void)out_size;
  Params p;
  p.X_aqi = d_in[0];
  p.X_meo = d_in[1];
  p.ctx   = d_in[2];
  p.adj   = d_in[3];
  p.adjn  = d_in[4];
  p.emb0 = d_in[5];  p.emb1 = d_in[6];
  p.emb2 = d_in[7];  p.emb3 = d_in[8];
  p.emb4 = d_in[9];  p.emb5 = d_in[10];
  p.emb6 = d_in[11]; p.emb7 = d_in[12];
  p.emb8 = d_in[13];
  p.Wxa = d_in[14]; p.Wxm = d_in[15];
  p.Wua = d_in[16]; p.Wum = d_in[17];
  p.a0 = d_in[18]; p.a1 = d_in[19];
  p.a2 = d_in[20]; p.a3 = d_in[21];
  p.wih_a = d_in[22]; p.whh_a = d_in[23];
  p.bih_a = d_in[24]; p.bhh_a = d_in[25];
  p.wih_m = d_in[26]; p.whh_m = d_in[27];
  p.bih_m = d_in[28]; p.bhh_m = d_in[29];
  p.Xae = (const int*)d_in[30];
  p.Xme = (const int*)d_in[31];
  p.out = d_out;
  hipLaunchKernelGGL(chgat_gru_kernel, dim3(1024), dim3(512), 0, stream, p);
}